// Round 1
// baseline (435.868 us; speedup 1.0000x reference)
//
#include <hip/hip_runtime.h>
#include <math.h>

#define NN 48
#define CC 512
#define KK 64
#define PP 1600
#define EPSF 1e-12f

// ---------------------------------------------------------------------------
// Kernel 1: fused (norm + attn + logits GEMM + softmax) per (n, 128-p tile).
// Computes w'[n,k,p] = softmax_k(logits)*hmp[p]*invnorm[p] and wsum[n,k].
// grid (13, N), block 256. Each block covers all 512 c for its 128 p.
// ---------------------------------------------------------------------------
__global__ __launch_bounds__(256) void kn_logits(
    const float* __restrict__ x, const float* __restrict__ conv_w,
    const float* __restrict__ attn_w, const float* __restrict__ attn_b,
    float* __restrict__ wg, float* __restrict__ wsum)
{
    __shared__ float x_t[32][128];     // [c_local][p_local]
    __shared__ float w_t[32][68];      // [c_local][k], padded to 68 (16B-aligned rows, conflict-shifted)
    __shared__ float attn_l[CC];
    __shared__ float red[8][128];
    __shared__ float redk[32][64];
    __shared__ float invn_l[128];
    __shared__ float hmp_l[128];

    const int n   = blockIdx.y;
    const int p0  = blockIdx.x * 128;
    const int tid = threadIdx.x;
    const int pg  = tid & 31;   // p-quad index (4 p per thread)
    const int kg  = tid >> 5;   // 0..7 (8 k per thread); also c-row group for staging
    const bool pval = (p0 + pg * 4) < PP;

    for (int i = tid; i < CC; i += 256) attn_l[i] = attn_w[i];

    float acc[8][4];
#pragma unroll
    for (int i = 0; i < 8; ++i)
#pragma unroll
        for (int j = 0; j < 4; ++j) acc[i][j] = 0.f;

    float ss[4] = {0.f, 0.f, 0.f, 0.f};
    float ad[4] = {0.f, 0.f, 0.f, 0.f};

    const float* xb = x + (size_t)n * CC * PP;

    __syncthreads();

    for (int ct = 0; ct < 16; ++ct) {
        // stage conv_w tile: w_t[c][k] = conv_w[k][ct*32+c]
#pragma unroll
        for (int j = 0; j < 8; ++j) {
            const int k = kg * 8 + j;
            w_t[pg][k] = conv_w[k * CC + ct * 32 + pg];
        }
        // stage x tile (coalesced float4) + accumulate sumsq & relu-attn dot
#pragma unroll
        for (int i = 0; i < 4; ++i) {
            const int c  = kg * 4 + i;       // local c 0..31
            const int cg = ct * 32 + c;
            float4 v = make_float4(0.f, 0.f, 0.f, 0.f);
            if (pval) v = *(const float4*)(xb + (size_t)cg * PP + p0 + pg * 4);
            *(float4*)&x_t[c][pg * 4] = v;
            const float aw = attn_l[cg];
            float va[4] = {v.x, v.y, v.z, v.w};
#pragma unroll
            for (int j = 0; j < 4; ++j) {
                ss[j] += va[j] * va[j];
                ad[j] += fmaxf(va[j], 0.f) * aw;
            }
        }
        __syncthreads();
#pragma unroll 8
        for (int cl = 0; cl < 32; ++cl) {
            const float4 xv = *(const float4*)&x_t[cl][pg * 4];
            const float4 wa = *(const float4*)&w_t[cl][kg * 8];
            const float4 wb = *(const float4*)&w_t[cl][kg * 8 + 4];
            float xa[4] = {xv.x, xv.y, xv.z, xv.w};
            float wk[8] = {wa.x, wa.y, wa.z, wa.w, wb.x, wb.y, wb.z, wb.w};
#pragma unroll
            for (int i = 0; i < 8; ++i)
#pragma unroll
                for (int j = 0; j < 4; ++j) acc[i][j] += wk[i] * xa[j];
        }
        __syncthreads();
    }

    // reduce channel sumsq across the 8 c-row groups -> invnorm per p
#pragma unroll
    for (int j = 0; j < 4; ++j) red[kg][pg * 4 + j] = ss[j];
    __syncthreads();
    if (tid < 128) {
        float S = 0.f;
#pragma unroll
        for (int l = 0; l < 8; ++l) S += red[l][tid];
        invn_l[tid] = 1.f / fmaxf(sqrtf(S), EPSF);
    }
    __syncthreads();
#pragma unroll
    for (int j = 0; j < 4; ++j) red[kg][pg * 4 + j] = ad[j];
    __syncthreads();
    if (tid < 128) {
        float A = 0.f;
#pragma unroll
        for (int l = 0; l < 8; ++l) A += red[l][tid];
        hmp_l[tid] = fmaxf(A + attn_b[0], 0.f);
    }
    __syncthreads();

    float inv4[4], hp4[4];
#pragma unroll
    for (int j = 0; j < 4; ++j) {
        inv4[j] = invn_l[pg * 4 + j];
        hp4[j]  = hmp_l[pg * 4 + j];
    }
    // logits = raw dot * invnorm (invnorm constant over c)
#pragma unroll
    for (int i = 0; i < 8; ++i)
#pragma unroll
        for (int j = 0; j < 4; ++j) acc[i][j] *= inv4[j];

    // softmax over k (64 values spread across 8 kg threads per p)
    float lm[4];
#pragma unroll
    for (int j = 0; j < 4; ++j) {
        float m = acc[0][j];
#pragma unroll
        for (int i = 1; i < 8; ++i) m = fmaxf(m, acc[i][j]);
        lm[j] = m;
    }
#pragma unroll
    for (int j = 0; j < 4; ++j) red[kg][pg * 4 + j] = lm[j];
    __syncthreads();
    float mx[4];
#pragma unroll
    for (int j = 0; j < 4; ++j) {
        float m = red[0][pg * 4 + j];
#pragma unroll
        for (int l = 1; l < 8; ++l) m = fmaxf(m, red[l][pg * 4 + j]);
        mx[j] = m;
    }
    __syncthreads();
    float lsum[4] = {0.f, 0.f, 0.f, 0.f};
#pragma unroll
    for (int i = 0; i < 8; ++i)
#pragma unroll
        for (int j = 0; j < 4; ++j) {
            acc[i][j] = expf(acc[i][j] - mx[j]);
            lsum[j] += acc[i][j];
        }
#pragma unroll
    for (int j = 0; j < 4; ++j) red[kg][pg * 4 + j] = lsum[j];
    __syncthreads();
    float sden[4];
#pragma unroll
    for (int j = 0; j < 4; ++j) {
        float s = 0.f;
#pragma unroll
        for (int l = 0; l < 8; ++l) s += red[l][pg * 4 + j];
        sden[j] = hp4[j] / s;    // fold hmp: w = e * sden
    }

    // w = e*hmp/sum; wsum partial per k reduced across pg via LDS
#pragma unroll
    for (int i = 0; i < 8; ++i) {
        float wk_ = 0.f;
#pragma unroll
        for (int j = 0; j < 4; ++j) {
            const float w = acc[i][j] * sden[j];
            acc[i][j] = w;
            wk_ += w;
        }
        redk[pg][kg * 8 + i] = pval ? wk_ : 0.f;
    }
    __syncthreads();
    if (tid < KK) {
        float t = 0.f;
#pragma unroll
        for (int q = 0; q < 32; ++q) t += redk[q][tid];
        atomicAdd(&wsum[n * KK + tid], t);
    }

    // store w' = w * invnorm (what term1 consumes)
    if (pval) {
        float* wgb = wg + (size_t)n * KK * PP + p0 + pg * 4;
#pragma unroll
        for (int i = 0; i < 8; ++i) {
            const int k = kg * 8 + i;
            float4 o;
            o.x = acc[i][0] * inv4[0]; o.y = acc[i][1] * inv4[1];
            o.z = acc[i][2] * inv4[2]; o.w = acc[i][3] * inv4[3];
            *(float4*)(wgb + (size_t)k * PP) = o;
        }
    }
}

// ---------------------------------------------------------------------------
// Kernel 2: term1[k,c] = sum_p w'[k,p] * x[c,p]   (per n, per 64-c tile,
// per p-half). grid (8, N, 2), block 256. Partials summed in kernel 3.
// ---------------------------------------------------------------------------
__global__ __launch_bounds__(256) void kn_term1(
    const float* __restrict__ x, const float* __restrict__ wg,
    float* __restrict__ term1p)
{
    __shared__ float wt[64][68];   // [p_local][k]
    __shared__ float xt[64][68];   // [p_local][c_local]
    const int n     = blockIdx.y;
    const int c0    = blockIdx.x * 64;
    const int h     = blockIdx.z;
    const int pbase = h * 800;
    const int tid   = threadIdx.x;
    const int ci    = tid & 15;    // c quad
    const int ki    = tid >> 4;    // k quad (0..15)
    const int pl    = tid & 63;
    const int r     = tid >> 6;    // 0..3

    float acc[4][4];
#pragma unroll
    for (int i = 0; i < 4; ++i)
#pragma unroll
        for (int j = 0; j < 4; ++j) acc[i][j] = 0.f;

    const float* xb = x + (size_t)n * CC * PP;
    const float* wb = wg + (size_t)n * KK * PP;

    for (int pt = 0; pt < 13; ++pt) {
        const int p0   = pbase + pt * 64;
        const int pcnt = min(64, 800 - pt * 64);   // last tile of each half: 32
        const bool v   = pl < pcnt;
#pragma unroll
        for (int j = 0; j < 16; ++j) {
            const int k = r * 16 + j;
            wt[pl][k] = v ? wb[(size_t)k * PP + p0 + pl] : 0.f;
        }
#pragma unroll
        for (int j = 0; j < 16; ++j) {
            const int c = r * 16 + j;
            xt[pl][c] = v ? xb[(size_t)(c0 + c) * PP + p0 + pl] : 0.f;
        }
        __syncthreads();
#pragma unroll 8
        for (int p = 0; p < 64; ++p) {
            const float4 kv = *(const float4*)&wt[p][ki * 4];
            const float4 cv = *(const float4*)&xt[p][ci * 4];
            float ka[4] = {kv.x, kv.y, kv.z, kv.w};
            float ca[4] = {cv.x, cv.y, cv.z, cv.w};
#pragma unroll
            for (int i = 0; i < 4; ++i)
#pragma unroll
                for (int j = 0; j < 4; ++j) acc[i][j] += ka[i] * ca[j];
        }
        __syncthreads();
    }

    float* ob = term1p + ((size_t)h * NN + n) * KK * CC + c0;
#pragma unroll
    for (int i = 0; i < 4; ++i) {
        float4 o = {acc[i][0], acc[i][1], acc[i][2], acc[i][3]};
        *(float4*)(ob + (size_t)(ki * 4 + i) * CC + ci * 4) = o;
    }
}

// ---------------------------------------------------------------------------
// Kernel 3: vlad = term1 - wsum*centroids; intra L2-normalize per (n,k);
// accumulate per-n global sumsq. grid (K, N), block 128 (4 c/thread).
// ---------------------------------------------------------------------------
__global__ __launch_bounds__(128) void kn_vlad(
    const float* __restrict__ term1p, const float* __restrict__ wsum,
    const float* __restrict__ cent, float* __restrict__ out,
    float* __restrict__ nsum)
{
    const int k   = blockIdx.x;
    const int n   = blockIdx.y;
    const int tid = threadIdx.x;
    const size_t base = ((size_t)n * KK + k) * CC;
    const size_t NKC  = (size_t)NN * KK * CC;
    const float ws = wsum[n * KK + k];
    const int c = tid * 4;

    float4 a  = *(const float4*)(term1p + base + c);
    float4 b  = *(const float4*)(term1p + NKC + base + c);
    float4 ce = *(const float4*)(cent + (size_t)k * CC + c);
    float4 v;
    v.x = a.x + b.x - ws * ce.x;
    v.y = a.y + b.y - ws * ce.y;
    v.z = a.z + b.z - ws * ce.z;
    v.w = a.w + b.w - ws * ce.w;

    float s = v.x * v.x + v.y * v.y + v.z * v.z + v.w * v.w;
#pragma unroll
    for (int o = 32; o >= 1; o >>= 1) s += __shfl_down(s, o, 64);

    __shared__ float rb[2];
    __shared__ float sinv;
    if ((tid & 63) == 0) rb[tid >> 6] = s;
    __syncthreads();
    if (tid == 0) {
        const float S   = rb[0] + rb[1];
        const float inv = 1.f / fmaxf(sqrtf(S), EPSF);
        sinv = inv;
        atomicAdd(&nsum[n], S * inv * inv);
    }
    __syncthreads();
    const float inv = sinv;
    float4 o4 = {v.x * inv, v.y * inv, v.z * inv, v.w * inv};
    *(float4*)(out + base + c) = o4;   // base == n*(K*C) + k*C : matches reshape(N, K*C)
}

// ---------------------------------------------------------------------------
// Kernel 4: global L2 normalize per n. grid (32, N), block 256, float4/thread.
// ---------------------------------------------------------------------------
__global__ __launch_bounds__(256) void kn_scale(
    float* __restrict__ out, const float* __restrict__ nsum)
{
    const int n = blockIdx.y;
    const size_t off = ((size_t)blockIdx.x * 256 + threadIdx.x) * 4;
    const float g = 1.f / fmaxf(sqrtf(nsum[n]), EPSF);
    float4 v = *(float4*)(out + (size_t)n * KK * CC + off);
    v.x *= g; v.y *= g; v.z *= g; v.w *= g;
    *(float4*)(out + (size_t)n * KK * CC + off) = v;
}

extern "C" void kernel_launch(void* const* d_in, const int* in_sizes, int n_in,
                              void* d_out, int out_size, void* d_ws, size_t ws_size,
                              hipStream_t stream)
{
    (void)in_sizes; (void)n_in; (void)out_size; (void)ws_size;
    const float* x      = (const float*)d_in[0];
    const float* conv_w = (const float*)d_in[1];
    const float* attn_w = (const float*)d_in[2];
    const float* attn_b = (const float*)d_in[3];
    const float* cent   = (const float*)d_in[4];
    float* out = (float*)d_out;

    // workspace layout (floats): w' [N*K*P] | wsum [N*K] | term1p [2*N*K*C] | nsum [N]
    float* wg     = (float*)d_ws;
    float* wsum   = wg + (size_t)NN * KK * PP;
    float* term1p = wsum + NN * KK;
    float* nsum   = term1p + (size_t)2 * NN * KK * CC;

    hipMemsetAsync(wsum, 0, NN * KK * sizeof(float), stream);
    hipMemsetAsync(nsum, 0, NN * sizeof(float), stream);

    kn_logits<<<dim3(13, NN), 256, 0, stream>>>(x, conv_w, attn_w, attn_b, wg, wsum);
    kn_term1 <<<dim3(8, NN, 2), 256, 0, stream>>>(x, wg, term1p);
    kn_vlad  <<<dim3(KK, NN), 128, 0, stream>>>(term1p, wsum, cent, out, nsum);
    kn_scale <<<dim3(32, NN), 256, 0, stream>>>(out, nsum);
}

// Round 2
// 318.419 us; speedup vs baseline: 1.3689x; 1.3689x over previous
//
#include <hip/hip_runtime.h>
#include <math.h>

#define NN 48
#define CC 512
#define KK 64
#define PP 1600
#define EPSF 1e-12f

typedef short short8 __attribute__((ext_vector_type(8)));
typedef float f32x4 __attribute__((ext_vector_type(4)));

static __device__ __forceinline__ unsigned short f2bf(float f) {
    unsigned u = __float_as_uint(f);
    u += 0x7fffu + ((u >> 16) & 1u);   // round-to-nearest-even
    return (unsigned short)(u >> 16);
}
static __device__ __forceinline__ unsigned pack2(float a, float b) {
    return (unsigned)f2bf(a) | ((unsigned)f2bf(b) << 16);
}

// ---------------------------------------------------------------------------
// Kernel 1: fused norm + attn + logits MFMA-GEMM + softmax.
// grid (13, N), block 256 (4 waves). Per block: 128 p, all 512 c.
// Emits w'[n,k,p] bf16 (= softmax*hmp*invnorm), wsum[n,k] (fp32 atomics),
// and optionally xbf = bf16(x) for kn_term1.
// ---------------------------------------------------------------------------
__global__ __launch_bounds__(256) void kn_logits(
    const float* __restrict__ x, const float* __restrict__ conv_w,
    const float* __restrict__ attn_w, const float* __restrict__ attn_b,
    unsigned short* __restrict__ wg, float* __restrict__ wsum,
    unsigned short* __restrict__ xbf)
{
    __shared__ unsigned short xt[64][140];   // [c_local][p] bf16, pad->140 (conflict-spread)
    __shared__ unsigned short cwb[64][72];   // [k][c_local] bf16, rows 144B (16B-aligned)
    __shared__ float attn_l[CC];
    __shared__ float red[8][128];
    __shared__ float invn_l[128];
    __shared__ float hmp_l[128];

    const int n = blockIdx.y, p0 = blockIdx.x * 128, tid = threadIdx.x;
    const int q = tid & 31, cg8 = tid >> 5;        // staging map: p-quad, c-row-group
    const int wave = tid >> 6, lane = tid & 63;
    const int lq = lane >> 4, lm = lane & 15;      // MFMA lane decomposition
    const bool pval = (p0 + q * 4) < PP;

    for (int i = tid; i < CC; i += 256) attn_l[i] = attn_w[i];

    f32x4 acc[4][2];
#pragma unroll
    for (int mt = 0; mt < 4; ++mt)
#pragma unroll
        for (int nt = 0; nt < 2; ++nt) acc[mt][nt] = (f32x4){0.f, 0.f, 0.f, 0.f};
    float ss[4] = {0.f, 0.f, 0.f, 0.f};
    float ad[4] = {0.f, 0.f, 0.f, 0.f};

    const float* xb = x + (size_t)n * CC * PP;
    __syncthreads();

    for (int cs = 0; cs < 8; ++cs) {
        const int c0 = cs * 64;
        // stage conv_w tile -> bf16 LDS [k][64c]
        {
            const int kr = tid >> 2, cq = tid & 3;
            const float* wp = conv_w + kr * CC + c0 + cq * 16;
#pragma unroll
            for (int j = 0; j < 4; ++j) {
                float4 v = *(const float4*)(wp + 4 * j);
                uint2 u = {pack2(v.x, v.y), pack2(v.z, v.w)};
                *(uint2*)&cwb[kr][cq * 16 + 4 * j] = u;
            }
        }
        // stage x tile (fp32 stats + bf16 LDS + bf16 global writeback)
#pragma unroll
        for (int j = 0; j < 8; ++j) {
            const int cl = cg8 * 8 + j, cg = c0 + cl;
            float4 v = make_float4(0.f, 0.f, 0.f, 0.f);
            if (pval) v = *(const float4*)(xb + (size_t)cg * PP + p0 + 4 * q);
            const float aw = attn_l[cg];
            ss[0] += v.x * v.x; ss[1] += v.y * v.y;
            ss[2] += v.z * v.z; ss[3] += v.w * v.w;
            ad[0] += fmaxf(v.x, 0.f) * aw; ad[1] += fmaxf(v.y, 0.f) * aw;
            ad[2] += fmaxf(v.z, 0.f) * aw; ad[3] += fmaxf(v.w, 0.f) * aw;
            uint2 u = {pack2(v.x, v.y), pack2(v.z, v.w)};
            *(uint2*)&xt[cl][4 * q] = u;
            if (xbf && pval)
                *(uint2*)(xbf + ((size_t)n * CC + cg) * PP + p0 + 4 * q) = u;
        }
        __syncthreads();
#pragma unroll
        for (int ks = 0; ks < 2; ++ks) {
            short8 af[4];
#pragma unroll
            for (int mt = 0; mt < 4; ++mt)
                af[mt] = *(const short8*)&cwb[mt * 16 + lm][ks * 32 + lq * 8];
#pragma unroll
            for (int nt = 0; nt < 2; ++nt) {
                const int pl = wave * 32 + nt * 16 + lm;
                const int cb = ks * 32 + lq * 8;
                short8 bv;
#pragma unroll
                for (int j = 0; j < 8; ++j) bv[j] = (short)xt[cb + j][pl];
#pragma unroll
                for (int mt = 0; mt < 4; ++mt)
                    acc[mt][nt] = __builtin_amdgcn_mfma_f32_16x16x32_bf16(
                        af[mt], bv, acc[mt][nt], 0, 0, 0);
            }
        }
        __syncthreads();
    }

    // block reductions: invnorm and hmp per p (fp32)
#pragma unroll
    for (int j = 0; j < 4; ++j) red[cg8][q * 4 + j] = ss[j];
    __syncthreads();
    if (tid < 128) {
        float S = 0.f;
#pragma unroll
        for (int l = 0; l < 8; ++l) S += red[l][tid];
        invn_l[tid] = 1.f / fmaxf(sqrtf(S), EPSF);
    }
    __syncthreads();
#pragma unroll
    for (int j = 0; j < 4; ++j) red[cg8][q * 4 + j] = ad[j];
    __syncthreads();
    if (tid < 128) {
        float A = 0.f;
#pragma unroll
        for (int l = 0; l < 8; ++l) A += red[l][tid];
        hmp_l[tid] = fmaxf(A + attn_b[0], 0.f);
    }
    __syncthreads();

    // softmax over k=64 per p, entirely in registers (C-layout + shfl_xor)
    float invv[2], sden[2];
#pragma unroll
    for (int nt = 0; nt < 2; ++nt) {
        const int pl = wave * 32 + nt * 16 + lm;
        const bool pv = (p0 + pl) < PP;
        const float inv = invn_l[pl];
        const float hp = pv ? hmp_l[pl] : 0.f;
        float mx = -1e30f;
#pragma unroll
        for (int mt = 0; mt < 4; ++mt)
#pragma unroll
            for (int r = 0; r < 4; ++r) {
                const float l = acc[mt][nt][r] * inv;
                acc[mt][nt][r] = l;
                mx = fmaxf(mx, l);
            }
        mx = fmaxf(mx, __shfl_xor(mx, 16));
        mx = fmaxf(mx, __shfl_xor(mx, 32));
        float s = 0.f;
#pragma unroll
        for (int mt = 0; mt < 4; ++mt)
#pragma unroll
            for (int r = 0; r < 4; ++r) {
                const float e = __expf(acc[mt][nt][r] - mx);
                acc[mt][nt][r] = e;
                s += e;
            }
        s += __shfl_xor(s, 16);
        s += __shfl_xor(s, 32);
        sden[nt] = hp / s;     // hp==0 for invalid p -> w==0 (no NaN path)
        invv[nt] = inv;
    }

    const int pl0 = wave * 32 + lm, pl1 = pl0 + 16;
    const bool v0 = (p0 + pl0) < PP, v1 = (p0 + pl1) < PP;
#pragma unroll
    for (int mt = 0; mt < 4; ++mt)
#pragma unroll
        for (int r = 0; r < 4; ++r) {
            const int k = mt * 16 + lq * 4 + r;
            const float w0 = acc[mt][0][r] * sden[0];
            const float w1 = acc[mt][1][r] * sden[1];
            float wk = w0 + w1;
#pragma unroll
            for (int o = 1; o < 16; o <<= 1) wk += __shfl_xor(wk, o);
            if (lm == 0) atomicAdd(&wsum[n * KK + k], wk);
            unsigned short* wr = wg + ((size_t)n * KK + k) * PP + p0;
            if (v0) wr[pl0] = f2bf(w0 * invv[0]);
            if (v1) wr[pl1] = f2bf(w1 * invv[1]);
        }
}

// ---------------------------------------------------------------------------
// Kernel 2: term1[k,c] = sum_p w'[k,p] * x[c,p] via MFMA (contraction over p;
// both operands p-contiguous -> b128 fragments). grid (4 c-chunks, N, 4 p-
// chunks) = 768 blocks (3/CU). Software-pipelined staging. XB: x from bf16
// sidecar; else convert fp32 x inline.
// ---------------------------------------------------------------------------
template <bool XB>
__global__ __launch_bounds__(256) void kn_term1(
    const float* __restrict__ xf, const unsigned short* __restrict__ xbf,
    const unsigned short* __restrict__ wgq, float* __restrict__ term1p)
{
    __shared__ unsigned short wt[64][40];    // [k][32p] bf16, rows 80B
    __shared__ unsigned short xt2[128][40];  // [c_local][32p] bf16
    const int c0 = blockIdx.x * 128, n = blockIdx.y, ph = blockIdx.z;
    const int tid = threadIdx.x;
    const int wave = tid >> 6, lane = tid & 63, lq = lane >> 4, lm = lane & 15;
    const int koff = (wave >> 1) * 32, coff = (wave & 1) * 64;
    const int s_begin = (50 * ph) >> 2, s_end = (50 * (ph + 1)) >> 2;

    const int rA = tid >> 2, cqA = tid & 3;          // A chunk (w')
    const int rB0 = tid >> 2, cqB0 = tid & 3;        // B chunk 0 (c rows 0..63)
    const int rB1 = (256 + tid) >> 2, cqB1 = tid & 3;// B chunk 1 (c rows 64..127)

    f32x4 acc[2][4];
#pragma unroll
    for (int mt = 0; mt < 2; ++mt)
#pragma unroll
        for (int nt = 0; nt < 4; ++nt) acc[mt][nt] = (f32x4){0.f, 0.f, 0.f, 0.f};

    const unsigned short* wb = wgq + (size_t)n * KK * PP;

    auto ldA = [&](int p0) -> uint4 {
        return *(const uint4*)(wb + (size_t)rA * PP + p0 + cqA * 8);
    };
    auto ldB = [&](int p0, int row, int cq) -> uint4 {
        if (XB) {
            return *(const uint4*)(xbf + ((size_t)n * CC + c0 + row) * PP + p0 + cq * 8);
        } else {
            const float* sp = xf + ((size_t)n * CC + c0 + row) * PP + p0 + cq * 8;
            float4 a = *(const float4*)sp, b = *(const float4*)(sp + 4);
            return make_uint4(pack2(a.x, a.y), pack2(a.z, a.w),
                              pack2(b.x, b.y), pack2(b.z, b.w));
        }
    };

    uint4 pa = ldA(s_begin * 32);
    uint4 pb0 = ldB(s_begin * 32, rB0, cqB0);
    uint4 pb1 = ldB(s_begin * 32, rB1, cqB1);

    for (int ps = s_begin; ps < s_end; ++ps) {
        *(uint4*)&wt[rA][cqA * 8] = pa;
        *(uint4*)&xt2[rB0][cqB0 * 8] = pb0;
        *(uint4*)&xt2[rB1][cqB1 * 8] = pb1;
        __syncthreads();
        uint4 na, nb0, nb1;
        if (ps + 1 < s_end) {                 // prefetch next tile (overlaps MFMA)
            const int p1 = (ps + 1) * 32;
            na = ldA(p1); nb0 = ldB(p1, rB0, cqB0); nb1 = ldB(p1, rB1, cqB1);
        }
        short8 af[2], bv[4];
#pragma unroll
        for (int mt = 0; mt < 2; ++mt)
            af[mt] = *(const short8*)&wt[koff + mt * 16 + lm][lq * 8];
#pragma unroll
        for (int nt = 0; nt < 4; ++nt)
            bv[nt] = *(const short8*)&xt2[coff + nt * 16 + lm][lq * 8];
#pragma unroll
        for (int mt = 0; mt < 2; ++mt)
#pragma unroll
            for (int nt = 0; nt < 4; ++nt)
                acc[mt][nt] = __builtin_amdgcn_mfma_f32_16x16x32_bf16(
                    af[mt], bv[nt], acc[mt][nt], 0, 0, 0);
        __syncthreads();
        pa = na; pb0 = nb0; pb1 = nb1;
    }

    float* ob = term1p + ((size_t)ph * NN + n) * KK * CC;
#pragma unroll
    for (int mt = 0; mt < 2; ++mt)
#pragma unroll
        for (int r = 0; r < 4; ++r) {
            const int k = koff + mt * 16 + lq * 4 + r;
#pragma unroll
            for (int nt = 0; nt < 4; ++nt)
                ob[(size_t)k * CC + c0 + coff + nt * 16 + lm] = acc[mt][nt][r];
        }
}

// ---------------------------------------------------------------------------
// Kernel 3: vlad = sum(term1 partials) - wsum*centroids; intra L2-normalize;
// per-n global sumsq. grid (K, N), block 128.
// ---------------------------------------------------------------------------
__global__ __launch_bounds__(128) void kn_vlad(
    const float* __restrict__ term1p, const float* __restrict__ wsum,
    const float* __restrict__ cent, float* __restrict__ out,
    float* __restrict__ nsum)
{
    const int k = blockIdx.x, n = blockIdx.y, tid = threadIdx.x;
    const size_t base = ((size_t)n * KK + k) * CC;
    const size_t NKC = (size_t)NN * KK * CC;
    const float ws = wsum[n * KK + k];
    const int c = tid * 4;

    float4 ce = *(const float4*)(cent + (size_t)k * CC + c);
    float4 v = {-ws * ce.x, -ws * ce.y, -ws * ce.z, -ws * ce.w};
#pragma unroll
    for (int h = 0; h < 4; ++h) {
        float4 a = *(const float4*)(term1p + h * NKC + base + c);
        v.x += a.x; v.y += a.y; v.z += a.z; v.w += a.w;
    }

    float s = v.x * v.x + v.y * v.y + v.z * v.z + v.w * v.w;
#pragma unroll
    for (int o = 32; o >= 1; o >>= 1) s += __shfl_down(s, o, 64);

    __shared__ float rb[2];
    __shared__ float sinv;
    if ((tid & 63) == 0) rb[tid >> 6] = s;
    __syncthreads();
    if (tid == 0) {
        const float S = rb[0] + rb[1];
        const float inv = 1.f / fmaxf(sqrtf(S), EPSF);
        sinv = inv;
        atomicAdd(&nsum[n], S * inv * inv);
    }
    __syncthreads();
    const float inv = sinv;
    float4 o4 = {v.x * inv, v.y * inv, v.z * inv, v.w * inv};
    *(float4*)(out + base + c) = o4;
}

// ---------------------------------------------------------------------------
// Kernel 4: global L2 normalize per n.
// ---------------------------------------------------------------------------
__global__ __launch_bounds__(256) void kn_scale(
    float* __restrict__ out, const float* __restrict__ nsum)
{
    const int n = blockIdx.y;
    const size_t off = ((size_t)blockIdx.x * 256 + threadIdx.x) * 4;
    const float g = 1.f / fmaxf(sqrtf(nsum[n]), EPSF);
    float4 v = *(float4*)(out + (size_t)n * KK * CC + off);
    v.x *= g; v.y *= g; v.z *= g; v.w *= g;
    *(float4*)(out + (size_t)n * KK * CC + off) = v;
}

extern "C" void kernel_launch(void* const* d_in, const int* in_sizes, int n_in,
                              void* d_out, int out_size, void* d_ws, size_t ws_size,
                              hipStream_t stream)
{
    (void)in_sizes; (void)n_in; (void)out_size;
    const float* x      = (const float*)d_in[0];
    const float* conv_w = (const float*)d_in[1];
    const float* attn_w = (const float*)d_in[2];
    const float* attn_b = (const float*)d_in[3];
    const float* cent   = (const float*)d_in[4];
    float* out = (float*)d_out;

    // ws layout: term1p[4][N][K][C] f32 | wsum f32 | nsum f32(pad) | wg bf16 | xbf bf16
    char* w = (char*)d_ws;
    float* term1p = (float*)w;            w += (size_t)4 * NN * KK * CC * 4;
    float* wsum   = (float*)w;            w += (size_t)NN * KK * 4;
    float* nsum   = (float*)w;            w += 256;
    unsigned short* wg  = (unsigned short*)w; w += (size_t)NN * KK * PP * 2;
    unsigned short* xbf = (unsigned short*)w;
    const size_t need_xb = (size_t)(w - (char*)d_ws) + (size_t)NN * CC * PP * 2;
    const bool xb = ws_size >= need_xb;

    hipMemsetAsync(wsum, 0, NN * KK * sizeof(float), stream);
    hipMemsetAsync(nsum, 0, NN * sizeof(float), stream);

    kn_logits<<<dim3(13, NN), 256, 0, stream>>>(x, conv_w, attn_w, attn_b,
                                                wg, wsum, xb ? xbf : nullptr);
    if (xb)
        kn_term1<true><<<dim3(4, NN, 4), 256, 0, stream>>>(x, xbf, wg, term1p);
    else
        kn_term1<false><<<dim3(4, NN, 4), 256, 0, stream>>>(x, xbf, wg, term1p);
    kn_vlad <<<dim3(KK, NN), 128, 0, stream>>>(term1p, wsum, cent, out, nsum);
    kn_scale<<<dim3(32, NN), 256, 0, stream>>>(out, nsum);
}